// Round 1
// baseline (19213.977 us; speedup 1.0000x reference)
//
#include <hip/hip_runtime.h>

typedef unsigned short u16;
typedef __bf16 bf16x8 __attribute__((ext_vector_type(8)));
typedef u16 u16x8 __attribute__((ext_vector_type(8)));
typedef u16 u16x4 __attribute__((ext_vector_type(4)));
typedef float f32x4 __attribute__((ext_vector_type(4)));

__device__ __forceinline__ u16 f2bf(float f){
    unsigned u = __builtin_bit_cast(unsigned, f);
    u = (u + 0x7fffu + ((u >> 16) & 1u)) >> 16;
    return (u16)u;
}
__device__ __forceinline__ float bf2f(u16 h){
    unsigned u = ((unsigned)h) << 16;
    return __builtin_bit_cast(float, u);
}
__device__ __forceinline__ float sigmoidf_(float x){ return 1.0f / (1.0f + __expf(-x)); }
__device__ __forceinline__ float tanhf_(float x){
    float e = __expf(2.0f * x);
    return 1.0f - 2.0f / (e + 1.0f);   // stable: x->-inf => -1, x->+inf (e=inf) => 1
}

// ---------------------------------------------------------------------------
// Kernel 0: pack Wx (4 gates) into transposed, gate-interleaved bf16:
//   Wxpt[pk][k], pk = 4*hcol + gate (gate order g,i,f,o), k = 0..127
// Also zero the group sync counters (stride 64B each).
// ---------------------------------------------------------------------------
__global__ __launch_bounds__(256) void lstm_pack(
    const float* __restrict__ Wgx, const float* __restrict__ Wix,
    const float* __restrict__ Wfx, const float* __restrict__ Wox,
    u16* __restrict__ Wxpt, unsigned* __restrict__ ctr)
{
    int idx = blockIdx.x * 256 + threadIdx.x;
    if (blockIdx.x == 0 && threadIdx.x < 16) ctr[threadIdx.x * 16] = 0u;
    const float* W4[4] = {Wgx, Wix, Wfx, Wox};
    if (idx < 1024 * 128){
        int pk = idx >> 7, k = idx & 127;
        int g = pk & 3, h = pk >> 2;
        Wxpt[idx] = f2bf(W4[g][k * 256 + h]);
    }
}

// ---------------------------------------------------------------------------
// Kernel 1: xg^T-style GEMM. Computes xg[row][pk] (row = t_local*256 + b),
// stored bf16, pk gate-interleaved. C^T orientation: D = Wxpt_tile * x^T.
// ---------------------------------------------------------------------------
__global__ __launch_bounds__(256, 2) void lstm_xg(
    const float* __restrict__ x, const u16* __restrict__ Wxpt,
    u16* __restrict__ xg, int ct0, int steps, int mtiles_total)
{
    __shared__ u16 Bt[32768];   // [256 pk][128 k] bf16, XOR-swizzled, 64 KiB
    const int tid = threadIdx.x;
    const int n0 = blockIdx.y << 8;             // pk tile base (0,256,512,768)

    // stage weight tile -> LDS (swizzled: byte ^= (row&7)<<4)
    for (int ii = 0; ii < 16; ++ii){
        int cid = ii * 256 + tid;               // 4096 x 16B chunks
        int nn = cid >> 4;
        int kc = (cid & 15) << 3;
        u16x8 v = *(const u16x8*)(Wxpt + (size_t)(n0 + nn) * 128 + kc);
        unsigned byte = (unsigned)(nn << 8) + (unsigned)(kc << 1);
        byte ^= ((nn & 7) << 4);
        *(u16x8*)((char*)Bt + byte) = v;
    }
    __syncthreads();

    const int w = tid >> 6, l = tid & 63;
    const int l15 = l & 15, l4 = l >> 4;

    for (int i = 0; i < 16; ++i){
        int mtile = blockIdx.x * 16 + i;
        if (mtile >= mtiles_total) break;
        int row = (mtile << 6) + (w << 4) + l15;      // chunk-local (t,b) row
        int t_glob = ct0 + (row >> 8);
        int b = row & 255;
        const float* xr = x + ((size_t)b * 1024 + t_glob) * 128;

        f32x4 acc[16];
        #pragma unroll
        for (int nt = 0; nt < 16; ++nt) acc[nt] = (f32x4){0.f, 0.f, 0.f, 0.f};

        #pragma unroll
        for (int kf = 0; kf < 4; ++kf){
            int k0 = kf * 32 + l4 * 8;
            f32x4 xa = *(const f32x4*)(xr + k0);
            f32x4 xb = *(const f32x4*)(xr + k0 + 4);
            u16x8 bu;
            bu[0]=f2bf(xa[0]); bu[1]=f2bf(xa[1]); bu[2]=f2bf(xa[2]); bu[3]=f2bf(xa[3]);
            bu[4]=f2bf(xb[0]); bu[5]=f2bf(xb[1]); bu[6]=f2bf(xb[2]); bu[7]=f2bf(xb[3]);
            bf16x8 bfX = __builtin_bit_cast(bf16x8, bu);
            #pragma unroll
            for (int nt = 0; nt < 16; ++nt){
                int nn = (nt << 4) + l15;
                unsigned byte = (unsigned)(nn << 8) + (unsigned)(k0 << 1);
                byte ^= ((nn & 7) << 4);
                u16x8 au = *(const u16x8*)((const char*)Bt + byte);
                bf16x8 afW = __builtin_bit_cast(bf16x8, au);
                acc[nt] = __builtin_amdgcn_mfma_f32_16x16x32_bf16(afW, bfX, acc[nt], 0, 0, 0);
            }
        }
        // store: lane writes 4 consecutive pk (u16x4) at its batch row
        #pragma unroll
        for (int nt = 0; nt < 16; ++nt){
            u16x4 o;
            o[0]=f2bf(acc[nt][0]); o[1]=f2bf(acc[nt][1]);
            o[2]=f2bf(acc[nt][2]); o[3]=f2bf(acc[nt][3]);
            *(u16x4*)(xg + (size_t)row * 1024 + n0 + (nt << 4) + (l4 << 2)) = o;
        }
    }
}

// ---------------------------------------------------------------------------
// Kernel 2: persistent recurrent scan. Grid 256 = 16 row-groups x 16 col-blocks.
// Block (mb,nb): batch rows [16mb,16mb+16), h-cols [16nb,16nb+16) (64 packed).
// Wh^T slice lives in VGPRs (hi+lo bf16). Per-group atomic counter sync.
// ---------------------------------------------------------------------------
__global__ __launch_bounds__(256, 1) void lstm_rec(
    const u16* __restrict__ xg,
    const float* __restrict__ Wgh, const float* __restrict__ Wih,
    const float* __restrict__ Wfh, const float* __restrict__ Woh,
    const float* __restrict__ bgx, const float* __restrict__ bgh,
    const float* __restrict__ bix, const float* __restrict__ bih,
    const float* __restrict__ bfx, const float* __restrict__ bfh,
    const float* __restrict__ box, const float* __restrict__ boh,
    u16* __restrict__ hhi, u16* __restrict__ hlo,
    float* __restrict__ c_ws, float* __restrict__ hT,
    unsigned* __restrict__ ctr, int ct0, int steps)
{
    const int tid = threadIdx.x;
    const int w = tid >> 6, l = tid & 63;
    const int l15 = l & 15, l4 = l >> 4;
    const int bid = blockIdx.x;
    const int mb = bid & 15, nb = bid >> 4;
    const int RB = mb << 4;
    const int P0 = (nb << 6) + (w << 4);        // wave's packed-col base

    // ---- one-time: Wh^T fragments (hi/lo split) into VGPRs ----
    const float* Wh4[4] = {Wgh, Wih, Wfh, Woh};
    int pkA = P0 + l15;
    const float* Wcol = Wh4[pkA & 3] + (pkA >> 2);
    bf16x8 whi[8], wlo[8];
    #pragma unroll
    for (int kf = 0; kf < 8; ++kf){
        u16x8 hi8, lo8;
        #pragma unroll
        for (int j = 0; j < 8; ++j){
            float v = Wcol[(size_t)(kf * 32 + l4 * 8 + j) * 256];
            u16 h = f2bf(v);
            hi8[j] = h;
            lo8[j] = f2bf(v - bf2f(h));
        }
        whi[kf] = __builtin_bit_cast(bf16x8, hi8);
        wlo[kf] = __builtin_bit_cast(bf16x8, lo8);
    }
    // ---- bias (bx+bh folded), c state ----
    const int hc = (P0 >> 2) + l4;              // this lane's h column
    const int r  = RB + l15;                    // this lane's batch row
    const float* bx4[4] = {bgx, bix, bfx, box};
    const float* bh4[4] = {bgh, bih, bfh, boh};
    float bias[4];
    #pragma unroll
    for (int g2 = 0; g2 < 4; ++g2) bias[g2] = bx4[g2][hc] + bh4[g2][hc];
    float c_val = 0.f;
    if (ct0 > 0) c_val = c_ws[(r << 8) + hc];

    unsigned* myctr = ctr + mb * 16;
    const int kb = l4 * 8;
    const int tend = ct0 + steps;

    for (int t = ct0; t < tend; ++t){
        // prefetch xg (independent of sync): lane's 4 gate pre-acts
        u16x4 xg4 = *(const u16x4*)(xg + ((size_t)(t - ct0) * 256 + r) * 1024
                                       + P0 + (l4 << 2));
        f32x4 a0 = {0,0,0,0}, a1 = {0,0,0,0}, a2 = {0,0,0,0};
        if (t > 0){
            unsigned target = (unsigned)(t << 4);
            while (__hip_atomic_load(myctr, __ATOMIC_RELAXED,
                                     __HIP_MEMORY_SCOPE_AGENT) < target) { }
            __builtin_amdgcn_fence(__ATOMIC_ACQUIRE, "agent");
            const u16* ph = hhi + (((size_t)((t - 1) & 1)) << 16) + (r << 8) + kb;
            const u16* pl = hlo + (((size_t)((t - 1) & 1)) << 16) + (r << 8) + kb;
            bf16x8 hb[8], lb[8];
            #pragma unroll
            for (int kf = 0; kf < 8; ++kf){
                hb[kf] = __builtin_bit_cast(bf16x8, *(const u16x8*)(ph + kf * 32));
                lb[kf] = __builtin_bit_cast(bf16x8, *(const u16x8*)(pl + kf * 32));
            }
            #pragma unroll
            for (int kf = 0; kf < 8; ++kf){
                a0 = __builtin_amdgcn_mfma_f32_16x16x32_bf16(whi[kf], hb[kf], a0, 0, 0, 0);
                a1 = __builtin_amdgcn_mfma_f32_16x16x32_bf16(wlo[kf], hb[kf], a1, 0, 0, 0);
                a2 = __builtin_amdgcn_mfma_f32_16x16x32_bf16(whi[kf], lb[kf], a2, 0, 0, 0);
            }
        }
        float gs = bf2f(xg4[0]) + bias[0] + a0[0] + a1[0] + a2[0];
        float is = bf2f(xg4[1]) + bias[1] + a0[1] + a1[1] + a2[1];
        float fs = bf2f(xg4[2]) + bias[2] + a0[2] + a1[2] + a2[2];
        float os = bf2f(xg4[3]) + bias[3] + a0[3] + a1[3] + a2[3];
        float gv = tanhf_(gs);
        float iv = sigmoidf_(is);
        float fv = sigmoidf_(fs);
        float ov = sigmoidf_(os);
        c_val = gv * iv + c_val * fv;
        float hv = tanhf_(c_val) * ov;

        u16 hh = f2bf(hv);
        u16 hl = f2bf(hv - bf2f(hh));
        size_t ho = (((size_t)(t & 1)) << 16) + (r << 8) + hc;
        hhi[ho] = hh;
        hlo[ho] = hl;
        if (t == 1023) hT[(r << 8) + hc] = hv;

        __syncthreads();   // all waves' stores drained (vmcnt(0) before s_barrier)
        if (tid == 0)
            __hip_atomic_fetch_add(myctr, 1u, __ATOMIC_RELEASE,
                                   __HIP_MEMORY_SCOPE_AGENT);
    }
    if (tend < 1024) c_ws[(r << 8) + hc] = c_val;
}

// ---------------------------------------------------------------------------
// Kernel 3: p = hT @ Wph + bph; softmax over 10.
// ---------------------------------------------------------------------------
__global__ __launch_bounds__(256) void lstm_head(
    const float* __restrict__ hT, const float* __restrict__ Wph,
    const float* __restrict__ bph, float* __restrict__ out)
{
    int b = threadIdx.x;
    float p[10];
    #pragma unroll
    for (int j = 0; j < 10; ++j) p[j] = bph[j];
    const float* hr = hT + (b << 8);
    for (int k = 0; k < 256; ++k){
        float h = hr[k];
        const float* wr = Wph + k * 10;
        #pragma unroll
        for (int j = 0; j < 10; ++j) p[j] += h * wr[j];
    }
    float m = p[0];
    #pragma unroll
    for (int j = 1; j < 10; ++j) m = fmaxf(m, p[j]);
    float s = 0.f;
    #pragma unroll
    for (int j = 0; j < 10; ++j){ p[j] = __expf(p[j] - m); s += p[j]; }
    float inv = 1.f / s;
    #pragma unroll
    for (int j = 0; j < 10; ++j) out[b * 10 + j] = p[j] * inv;
}

// ---------------------------------------------------------------------------
extern "C" void kernel_launch(void* const* d_in, const int* in_sizes, int n_in,
                              void* d_out, int out_size, void* d_ws, size_t ws_size,
                              hipStream_t stream)
{
    const float* x   = (const float*)d_in[0];
    const float* Wgx = (const float*)d_in[1];  const float* bgx = (const float*)d_in[2];
    const float* Wgh = (const float*)d_in[3];  const float* bgh = (const float*)d_in[4];
    const float* Wix = (const float*)d_in[5];  const float* bix = (const float*)d_in[6];
    const float* Wih = (const float*)d_in[7];  const float* bih = (const float*)d_in[8];
    const float* Wfx = (const float*)d_in[9];  const float* bfx = (const float*)d_in[10];
    const float* Wfh = (const float*)d_in[11]; const float* bfh = (const float*)d_in[12];
    const float* Wox = (const float*)d_in[13]; const float* box = (const float*)d_in[14];
    const float* Woh = (const float*)d_in[15]; const float* boh = (const float*)d_in[16];
    const float* Wph = (const float*)d_in[17]; const float* bph = (const float*)d_in[18];
    float* out = (float*)d_out;

    char* ws = (char*)d_ws;
    const size_t SEG = 262144;
    unsigned* ctr  = (unsigned*)(ws + 0);          // 16 counters, 64B stride
    u16*   hhi     = (u16*)  (ws + 4096);          // [2][256][256] bf16 hi
    u16*   hlo     = (u16*)  (ws + 4096 + 1*SEG);  // [2][256][256] bf16 lo
    float* cws     = (float*)(ws + 4096 + 2*SEG);  // [256][256] f32
    float* hT      = (float*)(ws + 4096 + 3*SEG);  // [256][256] f32
    u16*   Wxpt    = (u16*)  (ws + 4096 + 4*SEG);  // [1024][128] bf16
    u16*   xgbuf   = (u16*)  (ws + 4096 + 5*SEG);  // chunked [steps][256][1024] bf16
    size_t fixed = 4096 + 5*SEG;
    size_t avail = ws_size > fixed ? ws_size - fixed : 0;
    long chunk = (long)(avail / 524288);           // 512KB per timestep
    if (chunk < 1) chunk = 1;
    if (chunk > 1024) chunk = 1024;

    lstm_pack<<<dim3(512), dim3(256), 0, stream>>>(Wgx, Wix, Wfx, Wox, Wxpt, ctr);
    for (int ct0 = 0; ct0 < 1024; ct0 += (int)chunk){
        int steps = (int)((1024 - ct0 < chunk) ? (long)(1024 - ct0) : chunk);
        int mtiles = steps * 4;
        int mgroups = (mtiles + 15) / 16;
        lstm_xg<<<dim3(mgroups, 4), dim3(256), 0, stream>>>(
            x, Wxpt, xgbuf, ct0, steps, mtiles);
        lstm_rec<<<dim3(256), dim3(256), 0, stream>>>(
            xgbuf, Wgh, Wih, Wfh, Woh,
            bgx, bgh, bix, bih, bfx, bfh, box, boh,
            hhi, hlo, cws, hT, ctr, ct0, steps);
    }
    lstm_head<<<dim3(1), dim3(256), 0, stream>>>(hT, Wph, bph, out);
}

// Round 2
// 5246.655 us; speedup vs baseline: 3.6621x; 3.6621x over previous
//
#include <hip/hip_runtime.h>

typedef unsigned short u16;
typedef unsigned long long u64;
typedef __bf16 bf16x8 __attribute__((ext_vector_type(8)));
typedef u16 u16x8 __attribute__((ext_vector_type(8)));
typedef u16 u16x4 __attribute__((ext_vector_type(4)));
typedef float f32x4 __attribute__((ext_vector_type(4)));

__device__ __forceinline__ u16 f2bf(float f){
    unsigned u = __builtin_bit_cast(unsigned, f);
    u = (u + 0x7fffu + ((u >> 16) & 1u)) >> 16;
    return (u16)u;
}
__device__ __forceinline__ float bf2f(u16 h){
    unsigned u = ((unsigned)h) << 16;
    return __builtin_bit_cast(float, u);
}
__device__ __forceinline__ float sigmoidf_(float x){ return 1.0f / (1.0f + __expf(-x)); }
__device__ __forceinline__ float tanhf_(float x){
    float e = __expf(2.0f * x);
    return 1.0f - 2.0f / (e + 1.0f);   // stable: x->-inf => -1, x->+inf (e=inf) => 1
}

// ---------------------------------------------------------------------------
// Kernel 0: pack Wx (4 gates) into transposed, gate-interleaved bf16:
//   Wxpt[pk][k], pk = 4*hcol + gate (gate order g,i,f,o), k = 0..127
// Also zero the group sync counters (stride 64B each) via coherent stores.
// ---------------------------------------------------------------------------
__global__ __launch_bounds__(256) void lstm_pack(
    const float* __restrict__ Wgx, const float* __restrict__ Wix,
    const float* __restrict__ Wfx, const float* __restrict__ Wox,
    u16* __restrict__ Wxpt, unsigned* __restrict__ ctr)
{
    int idx = blockIdx.x * 256 + threadIdx.x;
    if (blockIdx.x == 0 && threadIdx.x < 16)
        __hip_atomic_store(ctr + threadIdx.x * 16, 0u,
                           __ATOMIC_RELAXED, __HIP_MEMORY_SCOPE_AGENT);
    const float* W4[4] = {Wgx, Wix, Wfx, Wox};
    if (idx < 1024 * 128){
        int pk = idx >> 7, k = idx & 127;
        int g = pk & 3, h = pk >> 2;
        Wxpt[idx] = f2bf(W4[g][k * 256 + h]);
    }
}

// ---------------------------------------------------------------------------
// Kernel 1: xg^T-style GEMM. Computes xg[row][pk] (row = t_local*256 + b),
// stored bf16, pk gate-interleaved. C^T orientation: D = Wxpt_tile * x^T.
// ---------------------------------------------------------------------------
__global__ __launch_bounds__(256, 2) void lstm_xg(
    const float* __restrict__ x, const u16* __restrict__ Wxpt,
    u16* __restrict__ xg, int ct0, int steps, int mtiles_total)
{
    __shared__ u16 Bt[32768];   // [256 pk][128 k] bf16, XOR-swizzled, 64 KiB
    const int tid = threadIdx.x;
    const int n0 = blockIdx.y << 8;             // pk tile base (0,256,512,768)

    // stage weight tile -> LDS (swizzled: byte ^= (row&7)<<4)
    for (int ii = 0; ii < 16; ++ii){
        int cid = ii * 256 + tid;               // 4096 x 16B chunks
        int nn = cid >> 4;
        int kc = (cid & 15) << 3;
        u16x8 v = *(const u16x8*)(Wxpt + (size_t)(n0 + nn) * 128 + kc);
        unsigned byte = (unsigned)(nn << 8) + (unsigned)(kc << 1);
        byte ^= ((nn & 7) << 4);
        *(u16x8*)((char*)Bt + byte) = v;
    }
    __syncthreads();

    const int w = tid >> 6, l = tid & 63;
    const int l15 = l & 15, l4 = l >> 4;

    for (int i = 0; i < 16; ++i){
        int mtile = blockIdx.x * 16 + i;
        if (mtile >= mtiles_total) break;
        int row = (mtile << 6) + (w << 4) + l15;      // chunk-local (t,b) row
        int t_glob = ct0 + (row >> 8);
        int b = row & 255;
        const float* xr = x + ((size_t)b * 1024 + t_glob) * 128;

        f32x4 acc[16];
        #pragma unroll
        for (int nt = 0; nt < 16; ++nt) acc[nt] = (f32x4){0.f, 0.f, 0.f, 0.f};

        #pragma unroll
        for (int kf = 0; kf < 4; ++kf){
            int k0 = kf * 32 + l4 * 8;
            f32x4 xa = *(const f32x4*)(xr + k0);
            f32x4 xb = *(const f32x4*)(xr + k0 + 4);
            u16x8 bu;
            bu[0]=f2bf(xa[0]); bu[1]=f2bf(xa[1]); bu[2]=f2bf(xa[2]); bu[3]=f2bf(xa[3]);
            bu[4]=f2bf(xb[0]); bu[5]=f2bf(xb[1]); bu[6]=f2bf(xb[2]); bu[7]=f2bf(xb[3]);
            bf16x8 bfX = __builtin_bit_cast(bf16x8, bu);
            #pragma unroll
            for (int nt = 0; nt < 16; ++nt){
                int nn = (nt << 4) + l15;
                unsigned byte = (unsigned)(nn << 8) + (unsigned)(k0 << 1);
                byte ^= ((nn & 7) << 4);
                u16x8 au = *(const u16x8*)((const char*)Bt + byte);
                bf16x8 afW = __builtin_bit_cast(bf16x8, au);
                acc[nt] = __builtin_amdgcn_mfma_f32_16x16x32_bf16(afW, bfX, acc[nt], 0, 0, 0);
            }
        }
        // store: lane writes 4 consecutive pk (u16x4) at its batch row
        #pragma unroll
        for (int nt = 0; nt < 16; ++nt){
            u16x4 o;
            o[0]=f2bf(acc[nt][0]); o[1]=f2bf(acc[nt][1]);
            o[2]=f2bf(acc[nt][2]); o[3]=f2bf(acc[nt][3]);
            *(u16x4*)(xg + (size_t)row * 1024 + n0 + (nt << 4) + (l4 << 2)) = o;
        }
    }
}

// ---------------------------------------------------------------------------
// Kernel 2: persistent recurrent scan. Grid 256 = 16 row-groups x 16 col-blocks.
// Block (mb,nb): batch rows [16mb,16mb+16), h-cols [16nb,16nb+16) (64 packed).
// Wh^T slice lives in VGPRs (hi+lo bf16). Fence-free exchange: all h traffic
// and sync counters use relaxed agent-scope atomics (sc0 sc1 -> Infinity
// Cache, the coherence point). No buffer_wbl2 / buffer_inv in the loop.
// ---------------------------------------------------------------------------
__global__ __launch_bounds__(256, 1) void lstm_rec(
    const u16* __restrict__ xg,
    const float* __restrict__ Wgh, const float* __restrict__ Wih,
    const float* __restrict__ Wfh, const float* __restrict__ Woh,
    const float* __restrict__ bgx, const float* __restrict__ bgh,
    const float* __restrict__ bix, const float* __restrict__ bih,
    const float* __restrict__ bfx, const float* __restrict__ bfh,
    const float* __restrict__ box, const float* __restrict__ boh,
    unsigned* __restrict__ h32,
    float* __restrict__ c_ws, float* __restrict__ hT,
    unsigned* __restrict__ ctr, int ct0, int steps)
{
    const int tid = threadIdx.x;
    const int w = tid >> 6, l = tid & 63;
    const int l15 = l & 15, l4 = l >> 4;
    const int bid = blockIdx.x;
    const int mb = bid & 15, nb = bid >> 4;
    const int RB = mb << 4;
    const int P0 = (nb << 6) + (w << 4);        // wave's packed-col base

    // ---- one-time: Wh^T fragments (hi/lo split) into VGPRs ----
    const float* Wh4[4] = {Wgh, Wih, Wfh, Woh};
    int pkA = P0 + l15;
    const float* Wcol = Wh4[pkA & 3] + (pkA >> 2);
    bf16x8 whi[8], wlo[8];
    #pragma unroll
    for (int kf = 0; kf < 8; ++kf){
        u16x8 hi8, lo8;
        #pragma unroll
        for (int j = 0; j < 8; ++j){
            float v = Wcol[(size_t)(kf * 32 + l4 * 8 + j) * 256];
            u16 h = f2bf(v);
            hi8[j] = h;
            lo8[j] = f2bf(v - bf2f(h));
        }
        whi[kf] = __builtin_bit_cast(bf16x8, hi8);
        wlo[kf] = __builtin_bit_cast(bf16x8, lo8);
    }
    // ---- bias (bx+bh folded), c state ----
    const int hc = (P0 >> 2) + l4;              // this lane's h column
    const int r  = RB + l15;                    // this lane's batch row
    const float* bx4[4] = {bgx, bix, bfx, box};
    const float* bh4[4] = {bgh, bih, bfh, boh};
    float bias[4];
    #pragma unroll
    for (int g2 = 0; g2 < 4; ++g2) bias[g2] = bx4[g2][hc] + bh4[g2][hc];
    float c_val = 0.f;
    if (ct0 > 0) c_val = c_ws[(r << 8) + hc];

    unsigned* myctr = ctr + mb * 16;
    const int kb = l4 * 8;                      // this lane's k-col base
    const int tend = ct0 + steps;

    for (int t = ct0; t < tend; ++t){
        // prefetch xg (independent of sync): lane's 4 gate pre-acts
        u16x4 xg4 = *(const u16x4*)(xg + ((size_t)(t - ct0) * 256 + r) * 1024
                                       + P0 + (l4 << 2));
        f32x4 a0 = {0,0,0,0}, a1 = {0,0,0,0}, a2 = {0,0,0,0};
        if (t > 0){
            unsigned target = (unsigned)(t << 4);
            while (__hip_atomic_load(myctr, __ATOMIC_RELAXED,
                                     __HIP_MEMORY_SCOPE_AGENT) < target) { }
            asm volatile("" ::: "memory");
            // load h[t-1]: 64 packed cols per lane, 64-bit coherent loads
            const unsigned* hbase = h32 + (((size_t)((t - 1) & 1)) << 16)
                                        + (r << 8) + kb;
            bf16x8 hb[8], lb[8];
            #pragma unroll
            for (int kf = 0; kf < 8; ++kf){
                const unsigned* p = hbase + kf * 32;
                u64 q0 = __hip_atomic_load((const u64*)(p + 0), __ATOMIC_RELAXED, __HIP_MEMORY_SCOPE_AGENT);
                u64 q1 = __hip_atomic_load((const u64*)(p + 2), __ATOMIC_RELAXED, __HIP_MEMORY_SCOPE_AGENT);
                u64 q2 = __hip_atomic_load((const u64*)(p + 4), __ATOMIC_RELAXED, __HIP_MEMORY_SCOPE_AGENT);
                u64 q3 = __hip_atomic_load((const u64*)(p + 6), __ATOMIC_RELAXED, __HIP_MEMORY_SCOPE_AGENT);
                u16x4 A = __builtin_bit_cast(u16x4, q0);
                u16x4 B = __builtin_bit_cast(u16x4, q1);
                u16x4 C = __builtin_bit_cast(u16x4, q2);
                u16x4 D = __builtin_bit_cast(u16x4, q3);
                u16x4 h01 = __builtin_shufflevector(A, B, 1, 3, 5, 7);   // hi parts
                u16x4 h23 = __builtin_shufflevector(C, D, 1, 3, 5, 7);
                u16x4 l01 = __builtin_shufflevector(A, B, 0, 2, 4, 6);   // lo parts
                u16x4 l23 = __builtin_shufflevector(C, D, 0, 2, 4, 6);
                hb[kf] = __builtin_bit_cast(bf16x8,
                    __builtin_shufflevector(h01, h23, 0,1,2,3,4,5,6,7));
                lb[kf] = __builtin_bit_cast(bf16x8,
                    __builtin_shufflevector(l01, l23, 0,1,2,3,4,5,6,7));
            }
            #pragma unroll
            for (int kf = 0; kf < 8; ++kf){
                a0 = __builtin_amdgcn_mfma_f32_16x16x32_bf16(whi[kf], hb[kf], a0, 0, 0, 0);
                a1 = __builtin_amdgcn_mfma_f32_16x16x32_bf16(wlo[kf], hb[kf], a1, 0, 0, 0);
                a2 = __builtin_amdgcn_mfma_f32_16x16x32_bf16(whi[kf], lb[kf], a2, 0, 0, 0);
            }
        }
        float gs = bf2f(xg4[0]) + bias[0] + a0[0] + a1[0] + a2[0];
        float is = bf2f(xg4[1]) + bias[1] + a0[1] + a1[1] + a2[1];
        float fs = bf2f(xg4[2]) + bias[2] + a0[2] + a1[2] + a2[2];
        float os = bf2f(xg4[3]) + bias[3] + a0[3] + a1[3] + a2[3];
        float gv = tanhf_(gs);
        float iv = sigmoidf_(is);
        float fv = sigmoidf_(fs);
        float ov = sigmoidf_(os);
        c_val = gv * iv + c_val * fv;
        float hv = tanhf_(c_val) * ov;

        u16 hh = f2bf(hv);
        u16 hl = f2bf(hv - bf2f(hh));
        unsigned hp = ((unsigned)hh << 16) | (unsigned)hl;
        __hip_atomic_store(h32 + (((size_t)(t & 1)) << 16) + (r << 8) + hc, hp,
                           __ATOMIC_RELAXED, __HIP_MEMORY_SCOPE_AGENT);
        if (t == 1023) hT[(r << 8) + hc] = hv;

        // __syncthreads emits s_waitcnt vmcnt(0) before s_barrier: all 4 waves'
        // coherent h stores are ack'd at the IC before tid0 bumps the counter.
        __syncthreads();
        if (tid == 0)
            __hip_atomic_fetch_add(myctr, 1u, __ATOMIC_RELAXED,
                                   __HIP_MEMORY_SCOPE_AGENT);
    }
    if (tend < 1024) c_ws[(r << 8) + hc] = c_val;
}

// ---------------------------------------------------------------------------
// Kernel 3: p = hT @ Wph + bph; softmax over 10.
// ---------------------------------------------------------------------------
__global__ __launch_bounds__(256) void lstm_head(
    const float* __restrict__ hT, const float* __restrict__ Wph,
    const float* __restrict__ bph, float* __restrict__ out)
{
    int b = threadIdx.x;
    float p[10];
    #pragma unroll
    for (int j = 0; j < 10; ++j) p[j] = bph[j];
    const float* hr = hT + (b << 8);
    for (int k = 0; k < 256; ++k){
        float h = hr[k];
        const float* wr = Wph + k * 10;
        #pragma unroll
        for (int j = 0; j < 10; ++j) p[j] += h * wr[j];
    }
    float m = p[0];
    #pragma unroll
    for (int j = 1; j < 10; ++j) m = fmaxf(m, p[j]);
    float s = 0.f;
    #pragma unroll
    for (int j = 0; j < 10; ++j){ p[j] = __expf(p[j] - m); s += p[j]; }
    float inv = 1.f / s;
    #pragma unroll
    for (int j = 0; j < 10; ++j) out[b * 10 + j] = p[j] * inv;
}

// ---------------------------------------------------------------------------
extern "C" void kernel_launch(void* const* d_in, const int* in_sizes, int n_in,
                              void* d_out, int out_size, void* d_ws, size_t ws_size,
                              hipStream_t stream)
{
    const float* x   = (const float*)d_in[0];
    const float* Wgx = (const float*)d_in[1];  const float* bgx = (const float*)d_in[2];
    const float* Wgh = (const float*)d_in[3];  const float* bgh = (const float*)d_in[4];
    const float* Wix = (const float*)d_in[5];  const float* bix = (const float*)d_in[6];
    const float* Wih = (const float*)d_in[7];  const float* bih = (const float*)d_in[8];
    const float* Wfx = (const float*)d_in[9];  const float* bfx = (const float*)d_in[10];
    const float* Wfh = (const float*)d_in[11]; const float* bfh = (const float*)d_in[12];
    const float* Wox = (const float*)d_in[13]; const float* box = (const float*)d_in[14];
    const float* Woh = (const float*)d_in[15]; const float* boh = (const float*)d_in[16];
    const float* Wph = (const float*)d_in[17]; const float* bph = (const float*)d_in[18];
    float* out = (float*)d_out;

    char* ws = (char*)d_ws;
    unsigned* ctr  = (unsigned*)(ws + 0);              // 16 counters, 64B stride
    unsigned* h32  = (unsigned*)(ws + 4096);           // [2][256][256] u32 (hi|lo)
    float* cws     = (float*)(ws + 4096 + 524288);     // [256][256] f32
    float* hT      = (float*)(ws + 4096 + 524288 + 262144);
    u16*   Wxpt    = (u16*)  (ws + 4096 + 524288 + 2*262144);  // [1024][128] bf16
    u16*   xgbuf   = (u16*)  (ws + 4096 + 524288 + 3*262144);  // [steps][256][1024] bf16
    size_t fixed = 4096 + 524288 + 3*262144;
    size_t avail = ws_size > fixed ? ws_size - fixed : 0;
    long chunk = (long)(avail / 524288);               // 512KB per timestep
    if (chunk < 1) chunk = 1;
    if (chunk > 1024) chunk = 1024;

    lstm_pack<<<dim3(512), dim3(256), 0, stream>>>(Wgx, Wix, Wfx, Wox, Wxpt, ctr);
    for (int ct0 = 0; ct0 < 1024; ct0 += (int)chunk){
        int steps = (int)((1024 - ct0 < chunk) ? (long)(1024 - ct0) : chunk);
        int mtiles = steps * 4;
        int mgroups = (mtiles + 15) / 16;
        lstm_xg<<<dim3(mgroups, 4), dim3(256), 0, stream>>>(
            x, Wxpt, xgbuf, ct0, steps, mtiles);
        lstm_rec<<<dim3(256), dim3(256), 0, stream>>>(
            xgbuf, Wgh, Wih, Wfh, Woh,
            bgx, bgh, bix, bih, bfx, bfh, box, boh,
            h32, cws, hT, ctr, ct0, steps);
    }
    lstm_head<<<dim3(1), dim3(256), 0, stream>>>(hT, Wph, bph, out);
}